// Round 18
// baseline (135.793 us; speedup 1.0000x reference)
//
#include <hip/hip_runtime.h>
#include <hip/hip_bf16.h>
#include <stdint.h>

// Problem constants: B=2, T=S=2048, C=1024, H=16, D=64
#define T_LEN 2048
#define CDIM  1024

typedef short bf16x8_t  __attribute__((ext_vector_type(8)));
typedef float f32x4_t   __attribute__((ext_vector_type(4)));
typedef float f32x16_t  __attribute__((ext_vector_type(16)));

__device__ __forceinline__ float fexp2(float x) {
  float r;
  asm("v_exp_f32 %0, %1" : "=v"(r) : "v"(x));
  return r;
}

__device__ __forceinline__ void gload_lds16(const void* gptr, void* lptr) {
  __builtin_amdgcn_global_load_lds(
      (const __attribute__((address_space(1))) unsigned int*)(gptr),
      (__attribute__((address_space(3))) unsigned int*)(lptr),
      16, 0, 0);
}

// counted-wait + raw barrier (no compiler vmcnt/lgkmcnt drain) — R11-proven
__device__ __forceinline__ void wait_vm0_barrier() {
  asm volatile("s_waitcnt vmcnt(0)" ::: "memory");
  __builtin_amdgcn_sched_barrier(0);
  __builtin_amdgcn_s_barrier();
  __builtin_amdgcn_sched_barrier(0);
}

__device__ __forceinline__ unsigned short f2bf(float f) {
  union { float f; unsigned int u; } v; v.f = f;
  unsigned int u = v.u;
  return (unsigned short)((u + 0x7fffu + ((u >> 16) & 1u)) >> 16);
}

__device__ __forceinline__ unsigned int pk_bf16(float lo, float hi) {
  unsigned int r;
  asm("v_cvt_pk_bf16_f32 %0, %1, %2" : "=v"(r) : "v"(lo), "v"(hi));
  return r;
}
__device__ __forceinline__ unsigned short bf1(float v) {
  return (unsigned short)pk_bf16(v, v);
}
__device__ __forceinline__ float bf2f(unsigned short u) {
  union { unsigned int u; float f; } v; v.u = ((unsigned int)u) << 16;
  return v.f;
}

// ---- cast f32 -> bf16 for q and p in one dispatch ----
__global__ __launch_bounds__(256) void cast2_f32_bf16(const float* __restrict__ x0,
                                                      const float* __restrict__ x1,
                                                      unsigned short* __restrict__ y0,
                                                      unsigned short* __restrict__ y1) {
  int i = blockIdx.x * 256 + threadIdx.x;
  const float* x = blockIdx.y ? x1 : x0;
  unsigned short* y = blockIdx.y ? y1 : y0;
  const float4* x4 = (const float4*)x;
  float4 a = x4[i * 2], b = x4[i * 2 + 1];
  union { unsigned short u[8]; uint4 v; } o;
  o.u[0] = f2bf(a.x); o.u[1] = f2bf(a.y); o.u[2] = f2bf(a.z); o.u[3] = f2bf(a.w);
  o.u[4] = f2bf(b.x); o.u[5] = f2bf(b.y); o.u[6] = f2bf(b.z); o.u[7] = f2bf(b.w);
  ((uint4*)y)[i] = o.v;
}

// ---- cast+transpose all 4 weights in one dispatch ----
__global__ __launch_bounds__(256) void transpose_cast4(const float* __restrict__ W0,
                                                       const float* __restrict__ W1,
                                                       const float* __restrict__ W2,
                                                       const float* __restrict__ W3,
                                                       unsigned short* __restrict__ Wall,
                                                       unsigned short* __restrict__ Wot) {
  __shared__ float tile[32][33];
  int z = blockIdx.z;
  const float* W = (z == 0) ? W0 : (z == 1) ? W1 : (z == 2) ? W2 : W3;
  unsigned short* Wt = (z < 3) ? (Wall + (size_t)z * 1024 * 1024) : Wot;
  int tx = threadIdx.x & 31, ty = threadIdx.x >> 5;
  int n0 = blockIdx.x * 32, k0 = blockIdx.y * 32;
#pragma unroll
  for (int i = 0; i < 4; ++i) {
    int r = ty + i * 8;
    tile[r][tx] = W[(size_t)(k0 + r) * CDIM + n0 + tx];
  }
  __syncthreads();
#pragma unroll
  for (int i = 0; i < 4; ++i) {
    int r = ty + i * 8;
    Wt[(size_t)(n0 + r) * CDIM + k0 + tx] = f2bf(tile[tx][r]);
  }
}

// ---- Fused QKV GEMM (R11-proven optimum): 128x64 tiles, true 2-phase dbuf ----
__global__ __launch_bounds__(256) void gemm_qkv(const unsigned short* __restrict__ qbm,
                                                const unsigned short* __restrict__ pbm,
                                                const unsigned short* __restrict__ Wall,
                                                unsigned short* __restrict__ Qh,
                                                unsigned short* __restrict__ Kh,
                                                unsigned short* __restrict__ Vt) {
  __shared__ unsigned short ldsA[2][128 * 64];
  __shared__ unsigned short ldsB[2][64 * 64];
  const int tid = threadIdx.x, lane = tid & 63, w = tid >> 6;
  const int bid = blockIdx.x;
  const int xcd = bid & 7, local = bid >> 3;
  const int pm = xcd & 3, pn = xcd >> 2;
  const int lm = local & 7, ln = local >> 3;
  const int mblk = pm * 8 + lm;
  const int nblk = pn * 24 + ln;
  const int m0 = mblk * 128;
  const int n0 = nblk * 64;
  const char* Ab = (const char*)((nblk < 16) ? qbm : pbm);
  const char* Bb = (const char*)Wall;
  f32x4_t acc[2][4] = {};

  auto stage = [&](int buf, int kt) {
#pragma unroll
    for (int it = 0; it < 4; ++it) {
      int ob = it * 4096 + w * 1024;
      int o = ob + lane * 16;
      int row = o >> 7, cin = o & 127;
      int cs = cin ^ ((row & 7) << 4);
      gload_lds16(Ab + (size_t)(m0 + row) * 2048 + kt * 128 + cs, (char*)ldsA[buf] + ob);
    }
#pragma unroll
    for (int it = 0; it < 2; ++it) {
      int ob = it * 4096 + w * 1024;
      int o = ob + lane * 16;
      int row = o >> 7, cin = o & 127;
      int cs = cin ^ ((row & 7) << 4);
      gload_lds16(Bb + (size_t)(n0 + row) * 2048 + kt * 128 + cs, (char*)ldsB[buf] + ob);
    }
  };

  stage(0, 0);
  wait_vm0_barrier();
  stage(1, 1);
  for (int kt = 0; kt < 16; ++kt) {
    const char* lA = (const char*)ldsA[kt & 1];
    const char* lB = (const char*)ldsB[kt & 1];
#pragma unroll
    for (int kf = 0; kf < 2; ++kf) {
      int c = kf * 64 + ((lane >> 4) << 4);
      bf16x8_t af[2], bfr[4];
#pragma unroll
      for (int mf = 0; mf < 2; ++mf) {
        int row = w * 32 + mf * 16 + (lane & 15);
        af[mf] = *(const bf16x8_t*)(lA + row * 128 + (c ^ ((row & 7) << 4)));
      }
#pragma unroll
      for (int nf = 0; nf < 4; ++nf) {
        int row = nf * 16 + (lane & 15);
        bfr[nf] = *(const bf16x8_t*)(lB + row * 128 + (c ^ ((row & 7) << 4)));
      }
#pragma unroll
      for (int mf = 0; mf < 2; ++mf)
#pragma unroll
        for (int nf = 0; nf < 4; ++nf)
          acc[mf][nf] = __builtin_amdgcn_mfma_f32_16x16x32_bf16(af[mf], bfr[nf], acc[mf][nf], 0, 0, 0);
    }
    if (kt < 15) {
      wait_vm0_barrier();
      if (kt + 2 < 16) stage(kt & 1, kt + 2);
    }
  }

  const float oscale = (nblk < 16) ? 0.18033688011112042f : 1.0f;  // 0.125*log2(e) for Q
#pragma unroll
  for (int mf = 0; mf < 2; ++mf)
#pragma unroll
    for (int nf = 0; nf < 4; ++nf)
#pragma unroll
      for (int j = 0; j < 4; ++j) {
        int row = m0 + w * 32 + mf * 16 + ((lane >> 4) << 2) + j;
        int col = n0 + nf * 16 + (lane & 15);
        float v = acc[mf][nf][j] * oscale;
        int b = row >> 11, ts = row & 2047;
        if (col < 1024) {
          int h = col >> 6, d = col & 63;
          Qh[(((size_t)(b * 16 + h)) * 2048 + ts) * 64 + d] = bf1(v);
        } else if (col < 2048) {
          int cc = col - 1024, h = cc >> 6, d = cc & 63;
          Kh[(((size_t)(b * 16 + h)) * 2048 + ts) * 64 + d] = bf1(v);
        } else {
          int cc = col - 2048, h = cc >> 6, d = cc & 63;
          Vt[(((size_t)(b * 16 + h)) * 64 + d) * 2048 + ts] = bf1(v);
        }
      }
}

// ---- final GEMM (R11-proven): 128x64 tile, true 2-phase dbuf, reads Ao ----
__global__ __launch_bounds__(256) void gemm_out(const unsigned short* __restrict__ A,
                                                const unsigned short* __restrict__ Bt,
                                                float* __restrict__ Out) {
  __shared__ unsigned short ldsA[2][128 * 64];
  __shared__ unsigned short ldsB[2][64 * 64];
  const int tid = threadIdx.x, lane = tid & 63, w = tid >> 6;
  const int bid = blockIdx.x;
  const int xcd = bid & 7, local = bid >> 3;
  const int pm = xcd & 3, pn = xcd >> 2;
  const int lm = local & 7, ln = local >> 3;
  const int m0 = (pm * 8 + lm) * 128;
  const int n0 = (pn * 8 + ln) * 64;
  const char* Ab = (const char*)A;
  const char* Bb = (const char*)Bt;
  f32x4_t acc[2][4] = {};

  auto stage = [&](int buf, int kt) {
#pragma unroll
    for (int it = 0; it < 4; ++it) {
      int ob = it * 4096 + w * 1024;
      int o = ob + lane * 16;
      int row = o >> 7, cin = o & 127;
      int cs = cin ^ ((row & 7) << 4);
      gload_lds16(Ab + (size_t)(m0 + row) * 2048 + kt * 128 + cs, (char*)ldsA[buf] + ob);
    }
#pragma unroll
    for (int it = 0; it < 2; ++it) {
      int ob = it * 4096 + w * 1024;
      int o = ob + lane * 16;
      int row = o >> 7, cin = o & 127;
      int cs = cin ^ ((row & 7) << 4);
      gload_lds16(Bb + (size_t)(n0 + row) * 2048 + kt * 128 + cs, (char*)ldsB[buf] + ob);
    }
  };

  stage(0, 0);
  wait_vm0_barrier();
  stage(1, 1);
  for (int kt = 0; kt < 16; ++kt) {
    const char* lA = (const char*)ldsA[kt & 1];
    const char* lB = (const char*)ldsB[kt & 1];
#pragma unroll
    for (int kf = 0; kf < 2; ++kf) {
      int c = kf * 64 + ((lane >> 4) << 4);
      bf16x8_t af[2], bfr[4];
#pragma unroll
      for (int mf = 0; mf < 2; ++mf) {
        int row = w * 32 + mf * 16 + (lane & 15);
        af[mf] = *(const bf16x8_t*)(lA + row * 128 + (c ^ ((row & 7) << 4)));
      }
#pragma unroll
      for (int nf = 0; nf < 4; ++nf) {
        int row = nf * 16 + (lane & 15);
        bfr[nf] = *(const bf16x8_t*)(lB + row * 128 + (c ^ ((row & 7) << 4)));
      }
#pragma unroll
      for (int mf = 0; mf < 2; ++mf)
#pragma unroll
        for (int nf = 0; nf < 4; ++nf)
          acc[mf][nf] = __builtin_amdgcn_mfma_f32_16x16x32_bf16(af[mf], bfr[nf], acc[mf][nf], 0, 0, 0);
    }
    if (kt < 15) {
      wait_vm0_barrier();
      if (kt + 2 < 16) stage(kt & 1, kt + 2);
    }
  }

#pragma unroll
  for (int mf = 0; mf < 2; ++mf)
#pragma unroll
    for (int nf = 0; nf < 4; ++nf)
#pragma unroll
      for (int j = 0; j < 4; ++j) {
        int row = m0 + w * 32 + mf * 16 + ((lane >> 4) << 2) + j;
        int col = n0 + nf * 16 + (lane & 15);
        Out[(size_t)row * 1024 + col] = acc[mf][nf][j];
      }
}

// ---- flash attention (R11-proven attn32 + T5 setprio): swapped-QK^T 32x32,
// max-free softmax, depth-2 pipeline; XCD-locality grid; bf16 O-partials for SPLIT2.
template <int SPLIT>
__global__ __launch_bounds__(256, 3) void attn32(const unsigned short* __restrict__ Qg,
                                                 const unsigned short* __restrict__ Kg,
                                                 const unsigned short* __restrict__ Vtg,
                                                 unsigned short* __restrict__ Ag,
                                                 unsigned short* __restrict__ OpA,
                                                 unsigned short* __restrict__ OpB,
                                                 float* __restrict__ Lp) {
  __shared__ unsigned short ldsK[3][64 * 64];  // 3 x 8 KB
  __shared__ unsigned short ldsV[2][64 * 64];  // 2 x 8 KB
  const int tid = threadIdx.x, lane = tid & 63, w = tid >> 6;
  const int hi = lane >> 5, ql = lane & 31;
  const int bid = blockIdx.x;
  int bh, z, qtile;
  if (SPLIT == 2) {
    int comb = bid & 63;
    qtile = bid >> 6;
    bh = comb >> 1;
    z = comb & 1;
  } else {
    bh = bid & 31;
    qtile = bid >> 5;
    z = 0;
  }
  const int q0 = qtile * 128 + w * 32;
  constexpr int NT = 2048 / SPLIT / 64;
  const int sBeg = z * (2048 / SPLIT);

  bf16x8_t qf[4];
#pragma unroll
  for (int kd = 0; kd < 4; ++kd)
    qf[kd] = *(const bf16x8_t*)(Qg + ((size_t)bh * T_LEN + q0 + ql) * 64 + kd * 16 + hi * 8);

  bf16x8_t ones;
#pragma unroll
  for (int i = 0; i < 8; ++i) ones[i] = (short)0x3F80;  // bf16 1.0

  f32x16_t oacc[2] = {};
  f32x16_t lacc = {};
  const f32x16_t vzero = {};

  const char* Kb = (const char*)(Kg + (size_t)bh * 2048 * 64);
  const char* Vb = (const char*)(Vtg + (size_t)bh * 64 * 2048);

  auto stageK = [&](int slot, int t) {
    int s0 = sBeg + t * 64;
#pragma unroll
    for (int it = 0; it < 2; ++it) {
      int ob = it * 4096 + w * 1024;
      int o = ob + lane * 16;
      int row = o >> 7, cin = o & 127;
      int cs = cin ^ ((row & 7) << 4);
      gload_lds16(Kb + (size_t)s0 * 128 + row * 128 + cs, (char*)ldsK[slot] + ob);
    }
  };
  auto stageV = [&](int slot, int t) {
    int s0 = sBeg + t * 64;
#pragma unroll
    for (int it = 0; it < 2; ++it) {
      int ob = it * 4096 + w * 1024;
      int o = ob + lane * 16;
      int row = o >> 7, cin = o & 127;
      int cs = cin ^ ((row & 7) << 4);
      gload_lds16(Vb + (size_t)s0 * 2 + (size_t)row * 4096 + cs, (char*)ldsV[slot] + ob);
    }
  };

  auto qk = [&](f32x16_t (&s)[2], int slot) {
    const char* lK = (const char*)ldsK[slot];
    __builtin_amdgcn_s_setprio(1);   // T5: favor MFMA-issuing wave (independent blocks/CU)
#pragma unroll
    for (int sub = 0; sub < 2; ++sub) {
      int row = sub * 32 + ql;
      int swz = (row & 7) << 4;
#pragma unroll
      for (int kd = 0; kd < 4; ++kd) {
        bf16x8_t kfrag = *(const bf16x8_t*)(lK + row * 128 + ((kd * 32 + hi * 16) ^ swz));
        s[sub] = __builtin_amdgcn_mfma_f32_32x32x16_bf16(kfrag, qf[kd], s[sub], 0, 0, 0);
      }
    }
    __builtin_amdgcn_s_setprio(0);
  };

  auto consume = [&](f32x16_t (&s)[2], int vslot) {
    const char* lV = (const char*)ldsV[vslot];
#pragma unroll
    for (int ks = 0; ks < 4; ++ks) {
      const int sub = ks >> 1, mA = (ks & 1) * 2, mB = mA + 1;
      float e0 = fexp2(s[sub][4 * mA + 0]), e1 = fexp2(s[sub][4 * mA + 1]);
      float e2 = fexp2(s[sub][4 * mA + 2]), e3 = fexp2(s[sub][4 * mA + 3]);
      float e4 = fexp2(s[sub][4 * mB + 0]), e5 = fexp2(s[sub][4 * mB + 1]);
      float e6 = fexp2(s[sub][4 * mB + 2]), e7 = fexp2(s[sub][4 * mB + 3]);
      unsigned int a0 = pk_bf16(e0, e1), a1 = pk_bf16(e2, e3);
      unsigned int b0 = pk_bf16(e4, e5), b1 = pk_bf16(e6, e7);
      asm("v_permlane32_swap_b32 %0, %1" : "+v"(a0), "+v"(b0));
      asm("v_permlane32_swap_b32 %0, %1" : "+v"(a1), "+v"(b1));
      union { unsigned int u[4]; bf16x8_t v; } P;
      P.u[0] = a0; P.u[1] = a1; P.u[2] = b0; P.u[3] = b1;
      __builtin_amdgcn_s_setprio(1);   // T5 around the PV MFMA cluster
      lacc = __builtin_amdgcn_mfma_f32_32x32x16_bf16(P.v, ones, lacc, 0, 0, 0);
#pragma unroll
      for (int dt = 0; dt < 2; ++dt) {
        int row = dt * 32 + ql;
        bf16x8_t vfrag = *(const bf16x8_t*)(lV + row * 128 + ((ks * 32 + hi * 16) ^ ((row & 7) << 4)));
        oacc[dt] = __builtin_amdgcn_mfma_f32_32x32x16_bf16(P.v, vfrag, oacc[dt], 0, 0, 0);
      }
      __builtin_amdgcn_s_setprio(0);
    }
  };

  f32x16_t sA[2] = {}, sB[2] = {};
  stageK(0, 0);
  stageV(0, 0);
  stageK(1, 1);
  __syncthreads();
  qk(sA, 0);

  for (int i = 0; i < NT; i += 2) {
    if (i + 2 < NT) stageK((i + 2) % 3, i + 2);
    if (i + 1 < NT) stageV((i + 1) & 1, i + 1);
    if (i + 1 < NT) { sB[0] = vzero; sB[1] = vzero; qk(sB, (i + 1) % 3); }
    consume(sA, i & 1);
    __syncthreads();
    if (i + 1 < NT) {
      if (i + 3 < NT) stageK((i + 3) % 3, i + 3);
      if (i + 2 < NT) stageV((i + 2) & 1, i + 2);
      if (i + 2 < NT) { sA[0] = vzero; sA[1] = vzero; qk(sA, (i + 2) % 3); }
      consume(sB, (i + 1) & 1);
      __syncthreads();
    }
  }

  const int b = bh >> 4, h = bh & 15;
  if (SPLIT == 1) {
#pragma unroll
    for (int grp = 0; grp < 4; ++grp)
#pragma unroll
      for (int r2 = 0; r2 < 4; ++r2) {
        int reg = grp * 4 + r2;
        float linv = 1.0f / lacc[reg];
        int t = q0 + 4 * hi + 8 * grp + r2;
#pragma unroll
        for (int dt = 0; dt < 2; ++dt) {
          int col = h * 64 + dt * 32 + ql;
          float v = oacc[dt][reg] * linv;
          Ag[((size_t)b * T_LEN + t) * CDIM + col] = bf1(v);
        }
      }
  } else {
    unsigned short* Op = z ? OpB : OpA;
#pragma unroll
    for (int grp = 0; grp < 4; ++grp)
#pragma unroll
      for (int r2 = 0; r2 < 4; ++r2) {
        int reg = grp * 4 + r2;
        int t = q0 + 4 * hi + 8 * grp + r2;
#pragma unroll
        for (int dt = 0; dt < 2; ++dt)
          Op[((size_t)b * T_LEN + t) * CDIM + h * 64 + dt * 32 + ql] = bf1(oacc[dt][reg]);
        if (ql == 0)
          Lp[(((size_t)z * 2 + b) * 16 + h) * T_LEN + t] = lacc[reg];
      }
  }
}

// ---- combine 2-way KV-split bf16 partials (R11-proven) ----
__global__ __launch_bounds__(256) void attn_combine(const unsigned short* __restrict__ O0,
                                                    const unsigned short* __restrict__ O1,
                                                    const float* __restrict__ Lp,
                                                    unsigned short* __restrict__ Ag) {
  int i = blockIdx.x * 256 + threadIdx.x;
  int c8 = i & 127, bt = i >> 7;
  int b = bt >> 11, t = bt & 2047;
  int c = c8 * 8, h = c >> 6;
  float l0 = Lp[(((size_t)0 * 2 + b) * 16 + h) * T_LEN + t];
  float l1 = Lp[(((size_t)1 * 2 + b) * 16 + h) * T_LEN + t];
  float inv = 1.0f / (l0 + l1);
  size_t off = (size_t)bt * CDIM + c;
  union { unsigned short u[8]; uint4 v; } a, bb, o;
  a.v  = *(const uint4*)(O0 + off);
  bb.v = *(const uint4*)(O1 + off);
  float s[8];
#pragma unroll
  for (int k = 0; k < 8; ++k) s[k] = (bf2f(a.u[k]) + bf2f(bb.u[k])) * inv;
  unsigned int p0 = pk_bf16(s[0], s[1]), p1 = pk_bf16(s[2], s[3]);
  unsigned int p2 = pk_bf16(s[4], s[5]), p3 = pk_bf16(s[6], s[7]);
  o.v = make_uint4(p0, p1, p2, p3);
  *(uint4*)(Ag + off) = o.v;
}

extern "C" void kernel_launch(void* const* d_in, const int* in_sizes, int n_in,
                              void* d_out, int out_size, void* d_ws, size_t ws_size,
                              hipStream_t stream) {
  const float* q  = (const float*)d_in[0];
  const float* p  = (const float*)d_in[1];
  const float* Wq = (const float*)d_in[2];
  const float* Wk = (const float*)d_in[3];
  const float* Wv = (const float*)d_in[4];
  const float* Wo = (const float*)d_in[5];

  char* ws = (char*)d_ws;
  const size_t MB = (size_t)1 << 20;
  unsigned short* qb   = (unsigned short*)(ws);            // 8 MB (dead after gemm_qkv)
  unsigned short* pb   = (unsigned short*)(ws + 8 * MB);   // 8 MB (dead after gemm_qkv)
  unsigned short* Wall = (unsigned short*)(ws + 16 * MB);  // 6 MB (dead after gemm_qkv)
  unsigned short* Wot  = (unsigned short*)(ws + 22 * MB);  // 2 MB
  unsigned short* Qh   = (unsigned short*)(ws + 24 * MB);  // 8 MB [B,H,T,D]
  unsigned short* Kh   = (unsigned short*)(ws + 32 * MB);  // 8 MB [B,H,S,D]
  unsigned short* Vt   = (unsigned short*)(ws + 40 * MB);  // 8 MB [B,H,D,S]
  unsigned short* Ao   = (unsigned short*)(ws + 48 * MB);  // 8 MB [B,T,C]

  cast2_f32_bf16<<<dim3(2048, 2), 256, 0, stream>>>(q, p, qb, pb);
  transpose_cast4<<<dim3(32, 32, 4), 256, 0, stream>>>(Wq, Wk, Wv, Wo, Wall, Wot);

  gemm_qkv<<<1536, 256, 0, stream>>>(qb, pb, Wall, Qh, Kh, Vt);

  if (ws_size >= 73 * MB) {
    unsigned short* O0 = (unsigned short*)(ws);            // overlays qb (dead)
    unsigned short* O1 = (unsigned short*)(ws + 56 * MB);
    float* Lp = (float*)(ws + 72 * MB);
    attn32<2><<<1024, 256, 0, stream>>>(Qh, Kh, Vt, nullptr, O0, O1, Lp);
    attn_combine<<<2048, 256, 0, stream>>>(O0, O1, Lp, Ao);
  } else {
    attn32<1><<<512, 256, 0, stream>>>(Qh, Kh, Vt, Ao, nullptr, nullptr, nullptr);
  }

  gemm_out<<<512, 256, 0, stream>>>(Ao, Wot, (float*)d_out);
}

// Round 19
// 130.184 us; speedup vs baseline: 1.0431x; 1.0431x over previous
//
#include <hip/hip_runtime.h>
#include <hip/hip_bf16.h>
#include <stdint.h>

// Problem constants: B=2, T=S=2048, C=1024, H=16, D=64
#define T_LEN 2048
#define CDIM  1024

typedef short bf16x8_t  __attribute__((ext_vector_type(8)));
typedef float f32x4_t   __attribute__((ext_vector_type(4)));
typedef float f32x16_t  __attribute__((ext_vector_type(16)));

__device__ __forceinline__ float fexp2(float x) {
  float r;
  asm("v_exp_f32 %0, %1" : "=v"(r) : "v"(x));
  return r;
}

__device__ __forceinline__ void gload_lds16(const void* gptr, void* lptr) {
  __builtin_amdgcn_global_load_lds(
      (const __attribute__((address_space(1))) unsigned int*)(gptr),
      (__attribute__((address_space(3))) unsigned int*)(lptr),
      16, 0, 0);
}

// counted-wait + raw barrier (no compiler vmcnt/lgkmcnt drain) — R11-proven
__device__ __forceinline__ void wait_vm0_barrier() {
  asm volatile("s_waitcnt vmcnt(0)" ::: "memory");
  __builtin_amdgcn_sched_barrier(0);
  __builtin_amdgcn_s_barrier();
  __builtin_amdgcn_sched_barrier(0);
}

__device__ __forceinline__ unsigned short f2bf(float f) {
  union { float f; unsigned int u; } v; v.f = f;
  unsigned int u = v.u;
  return (unsigned short)((u + 0x7fffu + ((u >> 16) & 1u)) >> 16);
}

__device__ __forceinline__ unsigned int pk_bf16(float lo, float hi) {
  unsigned int r;
  asm("v_cvt_pk_bf16_f32 %0, %1, %2" : "=v"(r) : "v"(lo), "v"(hi));
  return r;
}
__device__ __forceinline__ unsigned short bf1(float v) {
  return (unsigned short)pk_bf16(v, v);
}
__device__ __forceinline__ float bf2f(unsigned short u) {
  union { unsigned int u; float f; } v; v.u = ((unsigned int)u) << 16;
  return v.f;
}

// ---- cast f32 -> bf16 for q and p in one dispatch ----
__global__ __launch_bounds__(256) void cast2_f32_bf16(const float* __restrict__ x0,
                                                      const float* __restrict__ x1,
                                                      unsigned short* __restrict__ y0,
                                                      unsigned short* __restrict__ y1) {
  int i = blockIdx.x * 256 + threadIdx.x;
  const float* x = blockIdx.y ? x1 : x0;
  unsigned short* y = blockIdx.y ? y1 : y0;
  const float4* x4 = (const float4*)x;
  float4 a = x4[i * 2], b = x4[i * 2 + 1];
  union { unsigned short u[8]; uint4 v; } o;
  o.u[0] = f2bf(a.x); o.u[1] = f2bf(a.y); o.u[2] = f2bf(a.z); o.u[3] = f2bf(a.w);
  o.u[4] = f2bf(b.x); o.u[5] = f2bf(b.y); o.u[6] = f2bf(b.z); o.u[7] = f2bf(b.w);
  ((uint4*)y)[i] = o.v;
}

// ---- cast+transpose all 4 weights in one dispatch ----
__global__ __launch_bounds__(256) void transpose_cast4(const float* __restrict__ W0,
                                                       const float* __restrict__ W1,
                                                       const float* __restrict__ W2,
                                                       const float* __restrict__ W3,
                                                       unsigned short* __restrict__ Wall,
                                                       unsigned short* __restrict__ Wot) {
  __shared__ float tile[32][33];
  int z = blockIdx.z;
  const float* W = (z == 0) ? W0 : (z == 1) ? W1 : (z == 2) ? W2 : W3;
  unsigned short* Wt = (z < 3) ? (Wall + (size_t)z * 1024 * 1024) : Wot;
  int tx = threadIdx.x & 31, ty = threadIdx.x >> 5;
  int n0 = blockIdx.x * 32, k0 = blockIdx.y * 32;
#pragma unroll
  for (int i = 0; i < 4; ++i) {
    int r = ty + i * 8;
    tile[r][tx] = W[(size_t)(k0 + r) * CDIM + n0 + tx];
  }
  __syncthreads();
#pragma unroll
  for (int i = 0; i < 4; ++i) {
    int r = ty + i * 8;
    Wt[(size_t)(n0 + r) * CDIM + k0 + tx] = f2bf(tile[tx][r]);
  }
}

// ---- Fused QKV GEMM (R11-proven optimum): 128x64 tiles, true 2-phase dbuf ----
__global__ __launch_bounds__(256) void gemm_qkv(const unsigned short* __restrict__ qbm,
                                                const unsigned short* __restrict__ pbm,
                                                const unsigned short* __restrict__ Wall,
                                                unsigned short* __restrict__ Qh,
                                                unsigned short* __restrict__ Kh,
                                                unsigned short* __restrict__ Vt) {
  __shared__ unsigned short ldsA[2][128 * 64];
  __shared__ unsigned short ldsB[2][64 * 64];
  const int tid = threadIdx.x, lane = tid & 63, w = tid >> 6;
  const int bid = blockIdx.x;
  const int xcd = bid & 7, local = bid >> 3;
  const int pm = xcd & 3, pn = xcd >> 2;
  const int lm = local & 7, ln = local >> 3;
  const int mblk = pm * 8 + lm;
  const int nblk = pn * 24 + ln;
  const int m0 = mblk * 128;
  const int n0 = nblk * 64;
  const char* Ab = (const char*)((nblk < 16) ? qbm : pbm);
  const char* Bb = (const char*)Wall;
  f32x4_t acc[2][4] = {};

  auto stage = [&](int buf, int kt) {
#pragma unroll
    for (int it = 0; it < 4; ++it) {
      int ob = it * 4096 + w * 1024;
      int o = ob + lane * 16;
      int row = o >> 7, cin = o & 127;
      int cs = cin ^ ((row & 7) << 4);
      gload_lds16(Ab + (size_t)(m0 + row) * 2048 + kt * 128 + cs, (char*)ldsA[buf] + ob);
    }
#pragma unroll
    for (int it = 0; it < 2; ++it) {
      int ob = it * 4096 + w * 1024;
      int o = ob + lane * 16;
      int row = o >> 7, cin = o & 127;
      int cs = cin ^ ((row & 7) << 4);
      gload_lds16(Bb + (size_t)(n0 + row) * 2048 + kt * 128 + cs, (char*)ldsB[buf] + ob);
    }
  };

  stage(0, 0);
  wait_vm0_barrier();
  stage(1, 1);
  for (int kt = 0; kt < 16; ++kt) {
    const char* lA = (const char*)ldsA[kt & 1];
    const char* lB = (const char*)ldsB[kt & 1];
#pragma unroll
    for (int kf = 0; kf < 2; ++kf) {
      int c = kf * 64 + ((lane >> 4) << 4);
      bf16x8_t af[2], bfr[4];
#pragma unroll
      for (int mf = 0; mf < 2; ++mf) {
        int row = w * 32 + mf * 16 + (lane & 15);
        af[mf] = *(const bf16x8_t*)(lA + row * 128 + (c ^ ((row & 7) << 4)));
      }
#pragma unroll
      for (int nf = 0; nf < 4; ++nf) {
        int row = nf * 16 + (lane & 15);
        bfr[nf] = *(const bf16x8_t*)(lB + row * 128 + (c ^ ((row & 7) << 4)));
      }
#pragma unroll
      for (int mf = 0; mf < 2; ++mf)
#pragma unroll
        for (int nf = 0; nf < 4; ++nf)
          acc[mf][nf] = __builtin_amdgcn_mfma_f32_16x16x32_bf16(af[mf], bfr[nf], acc[mf][nf], 0, 0, 0);
    }
    if (kt < 15) {
      wait_vm0_barrier();
      if (kt + 2 < 16) stage(kt & 1, kt + 2);
    }
  }

  const float oscale = (nblk < 16) ? 0.18033688011112042f : 1.0f;  // 0.125*log2(e) for Q
#pragma unroll
  for (int mf = 0; mf < 2; ++mf)
#pragma unroll
    for (int nf = 0; nf < 4; ++nf)
#pragma unroll
      for (int j = 0; j < 4; ++j) {
        int row = m0 + w * 32 + mf * 16 + ((lane >> 4) << 2) + j;
        int col = n0 + nf * 16 + (lane & 15);
        float v = acc[mf][nf][j] * oscale;
        int b = row >> 11, ts = row & 2047;
        if (col < 1024) {
          int h = col >> 6, d = col & 63;
          Qh[(((size_t)(b * 16 + h)) * 2048 + ts) * 64 + d] = bf1(v);
        } else if (col < 2048) {
          int cc = col - 1024, h = cc >> 6, d = cc & 63;
          Kh[(((size_t)(b * 16 + h)) * 2048 + ts) * 64 + d] = bf1(v);
        } else {
          int cc = col - 2048, h = cc >> 6, d = cc & 63;
          Vt[(((size_t)(b * 16 + h)) * 64 + d) * 2048 + ts] = bf1(v);
        }
      }
}

// ---- final GEMM (R11-proven): 128x64 tile, true 2-phase dbuf, reads Ao ----
__global__ __launch_bounds__(256) void gemm_out(const unsigned short* __restrict__ A,
                                                const unsigned short* __restrict__ Bt,
                                                float* __restrict__ Out) {
  __shared__ unsigned short ldsA[2][128 * 64];
  __shared__ unsigned short ldsB[2][64 * 64];
  const int tid = threadIdx.x, lane = tid & 63, w = tid >> 6;
  const int bid = blockIdx.x;
  const int xcd = bid & 7, local = bid >> 3;
  const int pm = xcd & 3, pn = xcd >> 2;
  const int lm = local & 7, ln = local >> 3;
  const int m0 = (pm * 8 + lm) * 128;
  const int n0 = (pn * 8 + ln) * 64;
  const char* Ab = (const char*)A;
  const char* Bb = (const char*)Bt;
  f32x4_t acc[2][4] = {};

  auto stage = [&](int buf, int kt) {
#pragma unroll
    for (int it = 0; it < 4; ++it) {
      int ob = it * 4096 + w * 1024;
      int o = ob + lane * 16;
      int row = o >> 7, cin = o & 127;
      int cs = cin ^ ((row & 7) << 4);
      gload_lds16(Ab + (size_t)(m0 + row) * 2048 + kt * 128 + cs, (char*)ldsA[buf] + ob);
    }
#pragma unroll
    for (int it = 0; it < 2; ++it) {
      int ob = it * 4096 + w * 1024;
      int o = ob + lane * 16;
      int row = o >> 7, cin = o & 127;
      int cs = cin ^ ((row & 7) << 4);
      gload_lds16(Bb + (size_t)(n0 + row) * 2048 + kt * 128 + cs, (char*)ldsB[buf] + ob);
    }
  };

  stage(0, 0);
  wait_vm0_barrier();
  stage(1, 1);
  for (int kt = 0; kt < 16; ++kt) {
    const char* lA = (const char*)ldsA[kt & 1];
    const char* lB = (const char*)ldsB[kt & 1];
#pragma unroll
    for (int kf = 0; kf < 2; ++kf) {
      int c = kf * 64 + ((lane >> 4) << 4);
      bf16x8_t af[2], bfr[4];
#pragma unroll
      for (int mf = 0; mf < 2; ++mf) {
        int row = w * 32 + mf * 16 + (lane & 15);
        af[mf] = *(const bf16x8_t*)(lA + row * 128 + (c ^ ((row & 7) << 4)));
      }
#pragma unroll
      for (int nf = 0; nf < 4; ++nf) {
        int row = nf * 16 + (lane & 15);
        bfr[nf] = *(const bf16x8_t*)(lB + row * 128 + (c ^ ((row & 7) << 4)));
      }
#pragma unroll
      for (int mf = 0; mf < 2; ++mf)
#pragma unroll
        for (int nf = 0; nf < 4; ++nf)
          acc[mf][nf] = __builtin_amdgcn_mfma_f32_16x16x32_bf16(af[mf], bfr[nf], acc[mf][nf], 0, 0, 0);
    }
    if (kt < 15) {
      wait_vm0_barrier();
      if (kt + 2 < 16) stage(kt & 1, kt + 2);
    }
  }

#pragma unroll
  for (int mf = 0; mf < 2; ++mf)
#pragma unroll
    for (int nf = 0; nf < 4; ++nf)
#pragma unroll
      for (int j = 0; j < 4; ++j) {
        int row = m0 + w * 32 + mf * 16 + ((lane >> 4) << 2) + j;
        int col = n0 + nf * 16 + (lane & 15);
        Out[(size_t)row * 1024 + col] = acc[mf][nf][j];
      }
}

// ---- flash attention (R11-proven attn32, NO setprio): swapped-QK^T 32x32,
// max-free softmax, depth-2 pipeline; XCD-locality grid; bf16 O-partials for SPLIT2.
template <int SPLIT>
__global__ __launch_bounds__(256, 3) void attn32(const unsigned short* __restrict__ Qg,
                                                 const unsigned short* __restrict__ Kg,
                                                 const unsigned short* __restrict__ Vtg,
                                                 unsigned short* __restrict__ Ag,
                                                 unsigned short* __restrict__ OpA,
                                                 unsigned short* __restrict__ OpB,
                                                 float* __restrict__ Lp) {
  __shared__ unsigned short ldsK[3][64 * 64];  // 3 x 8 KB
  __shared__ unsigned short ldsV[2][64 * 64];  // 2 x 8 KB
  const int tid = threadIdx.x, lane = tid & 63, w = tid >> 6;
  const int hi = lane >> 5, ql = lane & 31;
  const int bid = blockIdx.x;
  int bh, z, qtile;
  if (SPLIT == 2) {
    int comb = bid & 63;
    qtile = bid >> 6;
    bh = comb >> 1;
    z = comb & 1;
  } else {
    bh = bid & 31;
    qtile = bid >> 5;
    z = 0;
  }
  const int q0 = qtile * 128 + w * 32;
  constexpr int NT = 2048 / SPLIT / 64;
  const int sBeg = z * (2048 / SPLIT);

  bf16x8_t qf[4];
#pragma unroll
  for (int kd = 0; kd < 4; ++kd)
    qf[kd] = *(const bf16x8_t*)(Qg + ((size_t)bh * T_LEN + q0 + ql) * 64 + kd * 16 + hi * 8);

  bf16x8_t ones;
#pragma unroll
  for (int i = 0; i < 8; ++i) ones[i] = (short)0x3F80;  // bf16 1.0

  f32x16_t oacc[2] = {};
  f32x16_t lacc = {};
  const f32x16_t vzero = {};

  const char* Kb = (const char*)(Kg + (size_t)bh * 2048 * 64);
  const char* Vb = (const char*)(Vtg + (size_t)bh * 64 * 2048);

  auto stageK = [&](int slot, int t) {
    int s0 = sBeg + t * 64;
#pragma unroll
    for (int it = 0; it < 2; ++it) {
      int ob = it * 4096 + w * 1024;
      int o = ob + lane * 16;
      int row = o >> 7, cin = o & 127;
      int cs = cin ^ ((row & 7) << 4);
      gload_lds16(Kb + (size_t)s0 * 128 + row * 128 + cs, (char*)ldsK[slot] + ob);
    }
  };
  auto stageV = [&](int slot, int t) {
    int s0 = sBeg + t * 64;
#pragma unroll
    for (int it = 0; it < 2; ++it) {
      int ob = it * 4096 + w * 1024;
      int o = ob + lane * 16;
      int row = o >> 7, cin = o & 127;
      int cs = cin ^ ((row & 7) << 4);
      gload_lds16(Vb + (size_t)s0 * 2 + (size_t)row * 4096 + cs, (char*)ldsV[slot] + ob);
    }
  };

  auto qk = [&](f32x16_t (&s)[2], int slot) {
    const char* lK = (const char*)ldsK[slot];
#pragma unroll
    for (int sub = 0; sub < 2; ++sub) {
      int row = sub * 32 + ql;
      int swz = (row & 7) << 4;
#pragma unroll
      for (int kd = 0; kd < 4; ++kd) {
        bf16x8_t kfrag = *(const bf16x8_t*)(lK + row * 128 + ((kd * 32 + hi * 16) ^ swz));
        s[sub] = __builtin_amdgcn_mfma_f32_32x32x16_bf16(kfrag, qf[kd], s[sub], 0, 0, 0);
      }
    }
  };

  auto consume = [&](f32x16_t (&s)[2], int vslot) {
    const char* lV = (const char*)ldsV[vslot];
#pragma unroll
    for (int ks = 0; ks < 4; ++ks) {
      const int sub = ks >> 1, mA = (ks & 1) * 2, mB = mA + 1;
      float e0 = fexp2(s[sub][4 * mA + 0]), e1 = fexp2(s[sub][4 * mA + 1]);
      float e2 = fexp2(s[sub][4 * mA + 2]), e3 = fexp2(s[sub][4 * mA + 3]);
      float e4 = fexp2(s[sub][4 * mB + 0]), e5 = fexp2(s[sub][4 * mB + 1]);
      float e6 = fexp2(s[sub][4 * mB + 2]), e7 = fexp2(s[sub][4 * mB + 3]);
      unsigned int a0 = pk_bf16(e0, e1), a1 = pk_bf16(e2, e3);
      unsigned int b0 = pk_bf16(e4, e5), b1 = pk_bf16(e6, e7);
      asm("v_permlane32_swap_b32 %0, %1" : "+v"(a0), "+v"(b0));
      asm("v_permlane32_swap_b32 %0, %1" : "+v"(a1), "+v"(b1));
      union { unsigned int u[4]; bf16x8_t v; } P;
      P.u[0] = a0; P.u[1] = a1; P.u[2] = b0; P.u[3] = b1;
      lacc = __builtin_amdgcn_mfma_f32_32x32x16_bf16(P.v, ones, lacc, 0, 0, 0);
#pragma unroll
      for (int dt = 0; dt < 2; ++dt) {
        int row = dt * 32 + ql;
        bf16x8_t vfrag = *(const bf16x8_t*)(lV + row * 128 + ((ks * 32 + hi * 16) ^ ((row & 7) << 4)));
        oacc[dt] = __builtin_amdgcn_mfma_f32_32x32x16_bf16(P.v, vfrag, oacc[dt], 0, 0, 0);
      }
    }
  };

  f32x16_t sA[2] = {}, sB[2] = {};
  stageK(0, 0);
  stageV(0, 0);
  stageK(1, 1);
  __syncthreads();
  qk(sA, 0);

  for (int i = 0; i < NT; i += 2) {
    if (i + 2 < NT) stageK((i + 2) % 3, i + 2);
    if (i + 1 < NT) stageV((i + 1) & 1, i + 1);
    if (i + 1 < NT) { sB[0] = vzero; sB[1] = vzero; qk(sB, (i + 1) % 3); }
    consume(sA, i & 1);
    __syncthreads();
    if (i + 1 < NT) {
      if (i + 3 < NT) stageK((i + 3) % 3, i + 3);
      if (i + 2 < NT) stageV((i + 2) & 1, i + 2);
      if (i + 2 < NT) { sA[0] = vzero; sA[1] = vzero; qk(sA, (i + 2) % 3); }
      consume(sB, (i + 1) & 1);
      __syncthreads();
    }
  }

  const int b = bh >> 4, h = bh & 15;
  if (SPLIT == 1) {
#pragma unroll
    for (int grp = 0; grp < 4; ++grp)
#pragma unroll
      for (int r2 = 0; r2 < 4; ++r2) {
        int reg = grp * 4 + r2;
        float linv = 1.0f / lacc[reg];
        int t = q0 + 4 * hi + 8 * grp + r2;
#pragma unroll
        for (int dt = 0; dt < 2; ++dt) {
          int col = h * 64 + dt * 32 + ql;
          float v = oacc[dt][reg] * linv;
          Ag[((size_t)b * T_LEN + t) * CDIM + col] = bf1(v);
        }
      }
  } else {
    unsigned short* Op = z ? OpB : OpA;
#pragma unroll
    for (int grp = 0; grp < 4; ++grp)
#pragma unroll
      for (int r2 = 0; r2 < 4; ++r2) {
        int reg = grp * 4 + r2;
        int t = q0 + 4 * hi + 8 * grp + r2;
#pragma unroll
        for (int dt = 0; dt < 2; ++dt)
          Op[((size_t)b * T_LEN + t) * CDIM + h * 64 + dt * 32 + ql] = bf1(oacc[dt][reg]);
        if (ql == 0)
          Lp[(((size_t)z * 2 + b) * 16 + h) * T_LEN + t] = lacc[reg];
      }
  }
}

// ---- combine 2-way KV-split bf16 partials (R11-proven) ----
__global__ __launch_bounds__(256) void attn_combine(const unsigned short* __restrict__ O0,
                                                    const unsigned short* __restrict__ O1,
                                                    const float* __restrict__ Lp,
                                                    unsigned short* __restrict__ Ag) {
  int i = blockIdx.x * 256 + threadIdx.x;
  int c8 = i & 127, bt = i >> 7;
  int b = bt >> 11, t = bt & 2047;
  int c = c8 * 8, h = c >> 6;
  float l0 = Lp[(((size_t)0 * 2 + b) * 16 + h) * T_LEN + t];
  float l1 = Lp[(((size_t)1 * 2 + b) * 16 + h) * T_LEN + t];
  float inv = 1.0f / (l0 + l1);
  size_t off = (size_t)bt * CDIM + c;
  union { unsigned short u[8]; uint4 v; } a, bb, o;
  a.v  = *(const uint4*)(O0 + off);
  bb.v = *(const uint4*)(O1 + off);
  float s[8];
#pragma unroll
  for (int k = 0; k < 8; ++k) s[k] = (bf2f(a.u[k]) + bf2f(bb.u[k])) * inv;
  unsigned int p0 = pk_bf16(s[0], s[1]), p1 = pk_bf16(s[2], s[3]);
  unsigned int p2 = pk_bf16(s[4], s[5]), p3 = pk_bf16(s[6], s[7]);
  o.v = make_uint4(p0, p1, p2, p3);
  *(uint4*)(Ag + off) = o.v;
}

extern "C" void kernel_launch(void* const* d_in, const int* in_sizes, int n_in,
                              void* d_out, int out_size, void* d_ws, size_t ws_size,
                              hipStream_t stream) {
  const float* q  = (const float*)d_in[0];
  const float* p  = (const float*)d_in[1];
  const float* Wq = (const float*)d_in[2];
  const float* Wk = (const float*)d_in[3];
  const float* Wv = (const float*)d_in[4];
  const float* Wo = (const float*)d_in[5];

  char* ws = (char*)d_ws;
  const size_t MB = (size_t)1 << 20;
  unsigned short* qb   = (unsigned short*)(ws);            // 8 MB (dead after gemm_qkv)
  unsigned short* pb   = (unsigned short*)(ws + 8 * MB);   // 8 MB (dead after gemm_qkv)
  unsigned short* Wall = (unsigned short*)(ws + 16 * MB);  // 6 MB (dead after gemm_qkv)
  unsigned short* Wot  = (unsigned short*)(ws + 22 * MB);  // 2 MB
  unsigned short* Qh   = (unsigned short*)(ws + 24 * MB);  // 8 MB [B,H,T,D]
  unsigned short* Kh   = (unsigned short*)(ws + 32 * MB);  // 8 MB [B,H,S,D]
  unsigned short* Vt   = (unsigned short*)(ws + 40 * MB);  // 8 MB [B,H,D,S]
  unsigned short* Ao   = (unsigned short*)(ws + 48 * MB);  // 8 MB [B,T,C]

  cast2_f32_bf16<<<dim3(2048, 2), 256, 0, stream>>>(q, p, qb, pb);
  transpose_cast4<<<dim3(32, 32, 4), 256, 0, stream>>>(Wq, Wk, Wv, Wo, Wall, Wot);

  gemm_qkv<<<1536, 256, 0, stream>>>(qb, pb, Wall, Qh, Kh, Vt);

  if (ws_size >= 73 * MB) {
    unsigned short* O0 = (unsigned short*)(ws);            // overlays qb (dead)
    unsigned short* O1 = (unsigned short*)(ws + 56 * MB);
    float* Lp = (float*)(ws + 72 * MB);
    attn32<2><<<1024, 256, 0, stream>>>(Qh, Kh, Vt, nullptr, O0, O1, Lp);
    attn_combine<<<2048, 256, 0, stream>>>(O0, O1, Lp, Ao);
  } else {
    attn32<1><<<512, 256, 0, stream>>>(Qh, Kh, Vt, Ao, nullptr, nullptr, nullptr);
  }

  gemm_out<<<512, 256, 0, stream>>>(Ao, Wot, (float*)d_out);
}

// Round 20
// 127.996 us; speedup vs baseline: 1.0609x; 1.0171x over previous
//
#include <hip/hip_runtime.h>
#include <hip/hip_bf16.h>
#include <stdint.h>

// Problem constants: B=2, T=S=2048, C=1024, H=16, D=64
#define T_LEN 2048
#define CDIM  1024

typedef short bf16x8_t  __attribute__((ext_vector_type(8)));
typedef float f32x4_t   __attribute__((ext_vector_type(4)));
typedef float f32x16_t  __attribute__((ext_vector_type(16)));

__device__ __forceinline__ float fexp2(float x) {
  float r;
  asm("v_exp_f32 %0, %1" : "=v"(r) : "v"(x));
  return r;
}

__device__ __forceinline__ void gload_lds16(const void* gptr, void* lptr) {
  __builtin_amdgcn_global_load_lds(
      (const __attribute__((address_space(1))) unsigned int*)(gptr),
      (__attribute__((address_space(3))) unsigned int*)(lptr),
      16, 0, 0);
}

// counted-wait + raw barrier (no compiler vmcnt/lgkmcnt drain) — R11-proven
__device__ __forceinline__ void wait_vm0_barrier() {
  asm volatile("s_waitcnt vmcnt(0)" ::: "memory");
  __builtin_amdgcn_sched_barrier(0);
  __builtin_amdgcn_s_barrier();
  __builtin_amdgcn_sched_barrier(0);
}

__device__ __forceinline__ unsigned short f2bf(float f) {
  union { float f; unsigned int u; } v; v.f = f;
  unsigned int u = v.u;
  return (unsigned short)((u + 0x7fffu + ((u >> 16) & 1u)) >> 16);
}

__device__ __forceinline__ unsigned int pk_bf16(float lo, float hi) {
  unsigned int r;
  asm("v_cvt_pk_bf16_f32 %0, %1, %2" : "=v"(r) : "v"(lo), "v"(hi));
  return r;
}
__device__ __forceinline__ unsigned short bf1(float v) {
  return (unsigned short)pk_bf16(v, v);
}
__device__ __forceinline__ float bf2f(unsigned short u) {
  union { unsigned int u; float f; } v; v.u = ((unsigned int)u) << 16;
  return v.f;
}

// ---- fused prologue: q/p cast (blocks 0..4095) + 4 weight transposes (4096..8191) ----
__global__ __launch_bounds__(256) void prologue(const float* __restrict__ q,
                                                const float* __restrict__ p,
                                                const float* __restrict__ W0,
                                                const float* __restrict__ W1,
                                                const float* __restrict__ W2,
                                                const float* __restrict__ W3,
                                                unsigned short* __restrict__ qb,
                                                unsigned short* __restrict__ pb,
                                                unsigned short* __restrict__ Wall,
                                                unsigned short* __restrict__ Wot) {
  __shared__ float tile[32][33];
  const int bid = blockIdx.x;
  if (bid < 4096) {
    // cast path: 2 x 2048 blocks, 8 f32 -> bf16 per thread
    const int which = bid >> 11;
    const int i = (bid & 2047) * 256 + threadIdx.x;
    const float* x = which ? p : q;
    unsigned short* y = which ? pb : qb;
    const float4* x4 = (const float4*)x;
    float4 a = x4[i * 2], b = x4[i * 2 + 1];
    union { unsigned short u[8]; uint4 v; } o;
    o.u[0] = f2bf(a.x); o.u[1] = f2bf(a.y); o.u[2] = f2bf(a.z); o.u[3] = f2bf(a.w);
    o.u[4] = f2bf(b.x); o.u[5] = f2bf(b.y); o.u[6] = f2bf(b.z); o.u[7] = f2bf(b.w);
    ((uint4*)y)[i] = o.v;
  } else {
    // transpose path: 4 x 1024 blocks of 32x32 tiles
    const int r = bid - 4096;
    const int z = r >> 10;
    const int xy = r & 1023;
    const int bx = xy & 31, by = xy >> 5;
    const float* W = (z == 0) ? W0 : (z == 1) ? W1 : (z == 2) ? W2 : W3;
    unsigned short* Wt = (z < 3) ? (Wall + (size_t)z * 1024 * 1024) : Wot;
    const int tx = threadIdx.x & 31, ty = threadIdx.x >> 5;
    const int n0 = bx * 32, k0 = by * 32;
#pragma unroll
    for (int i = 0; i < 4; ++i) {
      int rr = ty + i * 8;
      tile[rr][tx] = W[(size_t)(k0 + rr) * CDIM + n0 + tx];
    }
    __syncthreads();
#pragma unroll
    for (int i = 0; i < 4; ++i) {
      int rr = ty + i * 8;
      Wt[(size_t)(n0 + rr) * CDIM + k0 + tx] = f2bf(tile[tx][rr]);
    }
  }
}

// ---- Fused QKV GEMM (R11-proven optimum): 128x64 tiles, true 2-phase dbuf ----
__global__ __launch_bounds__(256) void gemm_qkv(const unsigned short* __restrict__ qbm,
                                                const unsigned short* __restrict__ pbm,
                                                const unsigned short* __restrict__ Wall,
                                                unsigned short* __restrict__ Qh,
                                                unsigned short* __restrict__ Kh,
                                                unsigned short* __restrict__ Vt) {
  __shared__ unsigned short ldsA[2][128 * 64];
  __shared__ unsigned short ldsB[2][64 * 64];
  const int tid = threadIdx.x, lane = tid & 63, w = tid >> 6;
  const int bid = blockIdx.x;
  const int xcd = bid & 7, local = bid >> 3;
  const int pm = xcd & 3, pn = xcd >> 2;
  const int lm = local & 7, ln = local >> 3;
  const int mblk = pm * 8 + lm;
  const int nblk = pn * 24 + ln;
  const int m0 = mblk * 128;
  const int n0 = nblk * 64;
  const char* Ab = (const char*)((nblk < 16) ? qbm : pbm);
  const char* Bb = (const char*)Wall;
  f32x4_t acc[2][4] = {};

  auto stage = [&](int buf, int kt) {
#pragma unroll
    for (int it = 0; it < 4; ++it) {
      int ob = it * 4096 + w * 1024;
      int o = ob + lane * 16;
      int row = o >> 7, cin = o & 127;
      int cs = cin ^ ((row & 7) << 4);
      gload_lds16(Ab + (size_t)(m0 + row) * 2048 + kt * 128 + cs, (char*)ldsA[buf] + ob);
    }
#pragma unroll
    for (int it = 0; it < 2; ++it) {
      int ob = it * 4096 + w * 1024;
      int o = ob + lane * 16;
      int row = o >> 7, cin = o & 127;
      int cs = cin ^ ((row & 7) << 4);
      gload_lds16(Bb + (size_t)(n0 + row) * 2048 + kt * 128 + cs, (char*)ldsB[buf] + ob);
    }
  };

  stage(0, 0);
  wait_vm0_barrier();
  stage(1, 1);
  for (int kt = 0; kt < 16; ++kt) {
    const char* lA = (const char*)ldsA[kt & 1];
    const char* lB = (const char*)ldsB[kt & 1];
#pragma unroll
    for (int kf = 0; kf < 2; ++kf) {
      int c = kf * 64 + ((lane >> 4) << 4);
      bf16x8_t af[2], bfr[4];
#pragma unroll
      for (int mf = 0; mf < 2; ++mf) {
        int row = w * 32 + mf * 16 + (lane & 15);
        af[mf] = *(const bf16x8_t*)(lA + row * 128 + (c ^ ((row & 7) << 4)));
      }
#pragma unroll
      for (int nf = 0; nf < 4; ++nf) {
        int row = nf * 16 + (lane & 15);
        bfr[nf] = *(const bf16x8_t*)(lB + row * 128 + (c ^ ((row & 7) << 4)));
      }
#pragma unroll
      for (int mf = 0; mf < 2; ++mf)
#pragma unroll
        for (int nf = 0; nf < 4; ++nf)
          acc[mf][nf] = __builtin_amdgcn_mfma_f32_16x16x32_bf16(af[mf], bfr[nf], acc[mf][nf], 0, 0, 0);
    }
    if (kt < 15) {
      wait_vm0_barrier();
      if (kt + 2 < 16) stage(kt & 1, kt + 2);
    }
  }

  const float oscale = (nblk < 16) ? 0.18033688011112042f : 1.0f;  // 0.125*log2(e) for Q
#pragma unroll
  for (int mf = 0; mf < 2; ++mf)
#pragma unroll
    for (int nf = 0; nf < 4; ++nf)
#pragma unroll
      for (int j = 0; j < 4; ++j) {
        int row = m0 + w * 32 + mf * 16 + ((lane >> 4) << 2) + j;
        int col = n0 + nf * 16 + (lane & 15);
        float v = acc[mf][nf][j] * oscale;
        int b = row >> 11, ts = row & 2047;
        if (col < 1024) {
          int h = col >> 6, d = col & 63;
          Qh[(((size_t)(b * 16 + h)) * 2048 + ts) * 64 + d] = bf1(v);
        } else if (col < 2048) {
          int cc = col - 1024, h = cc >> 6, d = cc & 63;
          Kh[(((size_t)(b * 16 + h)) * 2048 + ts) * 64 + d] = bf1(v);
        } else {
          int cc = col - 2048, h = cc >> 6, d = cc & 63;
          Vt[(((size_t)(b * 16 + h)) * 64 + d) * 2048 + ts] = bf1(v);
        }
      }
}

// ---- final GEMM (R11-proven): 128x64 tile, true 2-phase dbuf, reads Ao ----
__global__ __launch_bounds__(256) void gemm_out(const unsigned short* __restrict__ A,
                                                const unsigned short* __restrict__ Bt,
                                                float* __restrict__ Out) {
  __shared__ unsigned short ldsA[2][128 * 64];
  __shared__ unsigned short ldsB[2][64 * 64];
  const int tid = threadIdx.x, lane = tid & 63, w = tid >> 6;
  const int bid = blockIdx.x;
  const int xcd = bid & 7, local = bid >> 3;
  const int pm = xcd & 3, pn = xcd >> 2;
  const int lm = local & 7, ln = local >> 3;
  const int m0 = (pm * 8 + lm) * 128;
  const int n0 = (pn * 8 + ln) * 64;
  const char* Ab = (const char*)A;
  const char* Bb = (const char*)Bt;
  f32x4_t acc[2][4] = {};

  auto stage = [&](int buf, int kt) {
#pragma unroll
    for (int it = 0; it < 4; ++it) {
      int ob = it * 4096 + w * 1024;
      int o = ob + lane * 16;
      int row = o >> 7, cin = o & 127;
      int cs = cin ^ ((row & 7) << 4);
      gload_lds16(Ab + (size_t)(m0 + row) * 2048 + kt * 128 + cs, (char*)ldsA[buf] + ob);
    }
#pragma unroll
    for (int it = 0; it < 2; ++it) {
      int ob = it * 4096 + w * 1024;
      int o = ob + lane * 16;
      int row = o >> 7, cin = o & 127;
      int cs = cin ^ ((row & 7) << 4);
      gload_lds16(Bb + (size_t)(n0 + row) * 2048 + kt * 128 + cs, (char*)ldsB[buf] + ob);
    }
  };

  stage(0, 0);
  wait_vm0_barrier();
  stage(1, 1);
  for (int kt = 0; kt < 16; ++kt) {
    const char* lA = (const char*)ldsA[kt & 1];
    const char* lB = (const char*)ldsB[kt & 1];
#pragma unroll
    for (int kf = 0; kf < 2; ++kf) {
      int c = kf * 64 + ((lane >> 4) << 4);
      bf16x8_t af[2], bfr[4];
#pragma unroll
      for (int mf = 0; mf < 2; ++mf) {
        int row = w * 32 + mf * 16 + (lane & 15);
        af[mf] = *(const bf16x8_t*)(lA + row * 128 + (c ^ ((row & 7) << 4)));
      }
#pragma unroll
      for (int nf = 0; nf < 4; ++nf) {
        int row = nf * 16 + (lane & 15);
        bfr[nf] = *(const bf16x8_t*)(lB + row * 128 + (c ^ ((row & 7) << 4)));
      }
#pragma unroll
      for (int mf = 0; mf < 2; ++mf)
#pragma unroll
        for (int nf = 0; nf < 4; ++nf)
          acc[mf][nf] = __builtin_amdgcn_mfma_f32_16x16x32_bf16(af[mf], bfr[nf], acc[mf][nf], 0, 0, 0);
    }
    if (kt < 15) {
      wait_vm0_barrier();
      if (kt + 2 < 16) stage(kt & 1, kt + 2);
    }
  }

#pragma unroll
  for (int mf = 0; mf < 2; ++mf)
#pragma unroll
    for (int nf = 0; nf < 4; ++nf)
#pragma unroll
      for (int j = 0; j < 4; ++j) {
        int row = m0 + w * 32 + mf * 16 + ((lane >> 4) << 2) + j;
        int col = n0 + nf * 16 + (lane & 15);
        Out[(size_t)row * 1024 + col] = acc[mf][nf][j];
      }
}

// ---- flash attention (R11-proven attn32): swapped-QK^T 32x32, max-free softmax,
// depth-2 pipeline; XCD-locality grid; bf16 O-partials for SPLIT2.
template <int SPLIT>
__global__ __launch_bounds__(256, 3) void attn32(const unsigned short* __restrict__ Qg,
                                                 const unsigned short* __restrict__ Kg,
                                                 const unsigned short* __restrict__ Vtg,
                                                 unsigned short* __restrict__ Ag,
                                                 unsigned short* __restrict__ OpA,
                                                 unsigned short* __restrict__ OpB,
                                                 float* __restrict__ Lp) {
  __shared__ unsigned short ldsK[3][64 * 64];  // 3 x 8 KB
  __shared__ unsigned short ldsV[2][64 * 64];  // 2 x 8 KB
  const int tid = threadIdx.x, lane = tid & 63, w = tid >> 6;
  const int hi = lane >> 5, ql = lane & 31;
  const int bid = blockIdx.x;
  int bh, z, qtile;
  if (SPLIT == 2) {
    int comb = bid & 63;
    qtile = bid >> 6;
    bh = comb >> 1;
    z = comb & 1;
  } else {
    bh = bid & 31;
    qtile = bid >> 5;
    z = 0;
  }
  const int q0 = qtile * 128 + w * 32;
  constexpr int NT = 2048 / SPLIT / 64;
  const int sBeg = z * (2048 / SPLIT);

  bf16x8_t qf[4];
#pragma unroll
  for (int kd = 0; kd < 4; ++kd)
    qf[kd] = *(const bf16x8_t*)(Qg + ((size_t)bh * T_LEN + q0 + ql) * 64 + kd * 16 + hi * 8);

  bf16x8_t ones;
#pragma unroll
  for (int i = 0; i < 8; ++i) ones[i] = (short)0x3F80;  // bf16 1.0

  f32x16_t oacc[2] = {};
  f32x16_t lacc = {};
  const f32x16_t vzero = {};

  const char* Kb = (const char*)(Kg + (size_t)bh * 2048 * 64);
  const char* Vb = (const char*)(Vtg + (size_t)bh * 64 * 2048);

  auto stageK = [&](int slot, int t) {
    int s0 = sBeg + t * 64;
#pragma unroll
    for (int it = 0; it < 2; ++it) {
      int ob = it * 4096 + w * 1024;
      int o = ob + lane * 16;
      int row = o >> 7, cin = o & 127;
      int cs = cin ^ ((row & 7) << 4);
      gload_lds16(Kb + (size_t)s0 * 128 + row * 128 + cs, (char*)ldsK[slot] + ob);
    }
  };
  auto stageV = [&](int slot, int t) {
    int s0 = sBeg + t * 64;
#pragma unroll
    for (int it = 0; it < 2; ++it) {
      int ob = it * 4096 + w * 1024;
      int o = ob + lane * 16;
      int row = o >> 7, cin = o & 127;
      int cs = cin ^ ((row & 7) << 4);
      gload_lds16(Vb + (size_t)s0 * 2 + (size_t)row * 4096 + cs, (char*)ldsV[slot] + ob);
    }
  };

  auto qk = [&](f32x16_t (&s)[2], int slot) {
    const char* lK = (const char*)ldsK[slot];
#pragma unroll
    for (int sub = 0; sub < 2; ++sub) {
      int row = sub * 32 + ql;
      int swz = (row & 7) << 4;
#pragma unroll
      for (int kd = 0; kd < 4; ++kd) {
        bf16x8_t kfrag = *(const bf16x8_t*)(lK + row * 128 + ((kd * 32 + hi * 16) ^ swz));
        s[sub] = __builtin_amdgcn_mfma_f32_32x32x16_bf16(kfrag, qf[kd], s[sub], 0, 0, 0);
      }
    }
  };

  auto consume = [&](f32x16_t (&s)[2], int vslot) {
    const char* lV = (const char*)ldsV[vslot];
#pragma unroll
    for (int ks = 0; ks < 4; ++ks) {
      const int sub = ks >> 1, mA = (ks & 1) * 2, mB = mA + 1;
      float e0 = fexp2(s[sub][4 * mA + 0]), e1 = fexp2(s[sub][4 * mA + 1]);
      float e2 = fexp2(s[sub][4 * mA + 2]), e3 = fexp2(s[sub][4 * mA + 3]);
      float e4 = fexp2(s[sub][4 * mB + 0]), e5 = fexp2(s[sub][4 * mB + 1]);
      float e6 = fexp2(s[sub][4 * mB + 2]), e7 = fexp2(s[sub][4 * mB + 3]);
      unsigned int a0 = pk_bf16(e0, e1), a1 = pk_bf16(e2, e3);
      unsigned int b0 = pk_bf16(e4, e5), b1 = pk_bf16(e6, e7);
      asm("v_permlane32_swap_b32 %0, %1" : "+v"(a0), "+v"(b0));
      asm("v_permlane32_swap_b32 %0, %1" : "+v"(a1), "+v"(b1));
      union { unsigned int u[4]; bf16x8_t v; } P;
      P.u[0] = a0; P.u[1] = a1; P.u[2] = b0; P.u[3] = b1;
      lacc = __builtin_amdgcn_mfma_f32_32x32x16_bf16(P.v, ones, lacc, 0, 0, 0);
#pragma unroll
      for (int dt = 0; dt < 2; ++dt) {
        int row = dt * 32 + ql;
        bf16x8_t vfrag = *(const bf16x8_t*)(lV + row * 128 + ((ks * 32 + hi * 16) ^ ((row & 7) << 4)));
        oacc[dt] = __builtin_amdgcn_mfma_f32_32x32x16_bf16(P.v, vfrag, oacc[dt], 0, 0, 0);
      }
    }
  };

  f32x16_t sA[2] = {}, sB[2] = {};
  stageK(0, 0);
  stageV(0, 0);
  stageK(1, 1);
  __syncthreads();
  qk(sA, 0);

  for (int i = 0; i < NT; i += 2) {
    if (i + 2 < NT) stageK((i + 2) % 3, i + 2);
    if (i + 1 < NT) stageV((i + 1) & 1, i + 1);
    if (i + 1 < NT) { sB[0] = vzero; sB[1] = vzero; qk(sB, (i + 1) % 3); }
    consume(sA, i & 1);
    __syncthreads();
    if (i + 1 < NT) {
      if (i + 3 < NT) stageK((i + 3) % 3, i + 3);
      if (i + 2 < NT) stageV((i + 2) & 1, i + 2);
      if (i + 2 < NT) { sA[0] = vzero; sA[1] = vzero; qk(sA, (i + 2) % 3); }
      consume(sB, (i + 1) & 1);
      __syncthreads();
    }
  }

  const int b = bh >> 4, h = bh & 15;
  if (SPLIT == 1) {
#pragma unroll
    for (int grp = 0; grp < 4; ++grp)
#pragma unroll
      for (int r2 = 0; r2 < 4; ++r2) {
        int reg = grp * 4 + r2;
        float linv = 1.0f / lacc[reg];
        int t = q0 + 4 * hi + 8 * grp + r2;
#pragma unroll
        for (int dt = 0; dt < 2; ++dt) {
          int col = h * 64 + dt * 32 + ql;
          float v = oacc[dt][reg] * linv;
          Ag[((size_t)b * T_LEN + t) * CDIM + col] = bf1(v);
        }
      }
  } else {
    unsigned short* Op = z ? OpB : OpA;
#pragma unroll
    for (int grp = 0; grp < 4; ++grp)
#pragma unroll
      for (int r2 = 0; r2 < 4; ++r2) {
        int reg = grp * 4 + r2;
        int t = q0 + 4 * hi + 8 * grp + r2;
#pragma unroll
        for (int dt = 0; dt < 2; ++dt)
          Op[((size_t)b * T_LEN + t) * CDIM + h * 64 + dt * 32 + ql] = bf1(oacc[dt][reg]);
        if (ql == 0)
          Lp[(((size_t)z * 2 + b) * 16 + h) * T_LEN + t] = lacc[reg];
      }
  }
}

// ---- combine 2-way KV-split bf16 partials (R11-proven) ----
__global__ __launch_bounds__(256) void attn_combine(const unsigned short* __restrict__ O0,
                                                    const unsigned short* __restrict__ O1,
                                                    const float* __restrict__ Lp,
                                                    unsigned short* __restrict__ Ag) {
  int i = blockIdx.x * 256 + threadIdx.x;
  int c8 = i & 127, bt = i >> 7;
  int b = bt >> 11, t = bt & 2047;
  int c = c8 * 8, h = c >> 6;
  float l0 = Lp[(((size_t)0 * 2 + b) * 16 + h) * T_LEN + t];
  float l1 = Lp[(((size_t)1 * 2 + b) * 16 + h) * T_LEN + t];
  float inv = 1.0f / (l0 + l1);
  size_t off = (size_t)bt * CDIM + c;
  union { unsigned short u[8]; uint4 v; } a, bb, o;
  a.v  = *(const uint4*)(O0 + off);
  bb.v = *(const uint4*)(O1 + off);
  float s[8];
#pragma unroll
  for (int k = 0; k < 8; ++k) s[k] = (bf2f(a.u[k]) + bf2f(bb.u[k])) * inv;
  unsigned int p0 = pk_bf16(s[0], s[1]), p1 = pk_bf16(s[2], s[3]);
  unsigned int p2 = pk_bf16(s[4], s[5]), p3 = pk_bf16(s[6], s[7]);
  o.v = make_uint4(p0, p1, p2, p3);
  *(uint4*)(Ag + off) = o.v;
}

extern "C" void kernel_launch(void* const* d_in, const int* in_sizes, int n_in,
                              void* d_out, int out_size, void* d_ws, size_t ws_size,
                              hipStream_t stream) {
  const float* q  = (const float*)d_in[0];
  const float* p  = (const float*)d_in[1];
  const float* Wq = (const float*)d_in[2];
  const float* Wk = (const float*)d_in[3];
  const float* Wv = (const float*)d_in[4];
  const float* Wo = (const float*)d_in[5];

  char* ws = (char*)d_ws;
  const size_t MB = (size_t)1 << 20;
  unsigned short* qb   = (unsigned short*)(ws);            // 8 MB (dead after gemm_qkv)
  unsigned short* pb   = (unsigned short*)(ws + 8 * MB);   // 8 MB (dead after gemm_qkv)
  unsigned short* Wall = (unsigned short*)(ws + 16 * MB);  // 6 MB (dead after gemm_qkv)
  unsigned short* Wot  = (unsigned short*)(ws + 22 * MB);  // 2 MB
  unsigned short* Qh   = (unsigned short*)(ws + 24 * MB);  // 8 MB [B,H,T,D]
  unsigned short* Kh   = (unsigned short*)(ws + 32 * MB);  // 8 MB [B,H,S,D]
  unsigned short* Vt   = (unsigned short*)(ws + 40 * MB);  // 8 MB [B,H,D,S]
  unsigned short* Ao   = (unsigned short*)(ws + 48 * MB);  // 8 MB [B,T,C]

  prologue<<<8192, 256, 0, stream>>>(q, p, Wq, Wk, Wv, Wo, qb, pb, Wall, Wot);

  gemm_qkv<<<1536, 256, 0, stream>>>(qb, pb, Wall, Qh, Kh, Vt);

  if (ws_size >= 73 * MB) {
    unsigned short* O0 = (unsigned short*)(ws);            // overlays qb (dead)
    unsigned short* O1 = (unsigned short*)(ws + 56 * MB);
    float* Lp = (float*)(ws + 72 * MB);
    attn32<2><<<1024, 256, 0, stream>>>(Qh, Kh, Vt, nullptr, O0, O1, Lp);
    attn_combine<<<2048, 256, 0, stream>>>(O0, O1, Lp, Ao);
  } else {
    attn32<1><<<512, 256, 0, stream>>>(Qh, Kh, Vt, Ao, nullptr, nullptr, nullptr);
  }

  gemm_out<<<512, 256, 0, stream>>>(Ao, Wot, (float*)d_out);
}

// Round 21
// 127.564 us; speedup vs baseline: 1.0645x; 1.0034x over previous
//
#include <hip/hip_runtime.h>
#include <hip/hip_bf16.h>
#include <stdint.h>

// Problem constants: B=2, T=S=2048, C=1024, H=16, D=64
#define T_LEN 2048
#define CDIM  1024

typedef short bf16x8_t  __attribute__((ext_vector_type(8)));
typedef float f32x4_t   __attribute__((ext_vector_type(4)));
typedef float f32x16_t  __attribute__((ext_vector_type(16)));

__device__ __forceinline__ float fexp2(float x) {
  float r;
  asm("v_exp_f32 %0, %1" : "=v"(r) : "v"(x));
  return r;
}

__device__ __forceinline__ void gload_lds16(const void* gptr, void* lptr) {
  __builtin_amdgcn_global_load_lds(
      (const __attribute__((address_space(1))) unsigned int*)(gptr),
      (__attribute__((address_space(3))) unsigned int*)(lptr),
      16, 0, 0);
}

// counted-wait + raw barrier (no compiler vmcnt/lgkmcnt drain) — R11-proven
__device__ __forceinline__ void wait_vm0_barrier() {
  asm volatile("s_waitcnt vmcnt(0)" ::: "memory");
  __builtin_amdgcn_sched_barrier(0);
  __builtin_amdgcn_s_barrier();
  __builtin_amdgcn_sched_barrier(0);
}

__device__ __forceinline__ unsigned short f2bf(float f) {
  union { float f; unsigned int u; } v; v.f = f;
  unsigned int u = v.u;
  return (unsigned short)((u + 0x7fffu + ((u >> 16) & 1u)) >> 16);
}

__device__ __forceinline__ unsigned int pk_bf16(float lo, float hi) {
  unsigned int r;
  asm("v_cvt_pk_bf16_f32 %0, %1, %2" : "=v"(r) : "v"(lo), "v"(hi));
  return r;
}
__device__ __forceinline__ unsigned short bf1(float v) {
  return (unsigned short)pk_bf16(v, v);
}
__device__ __forceinline__ float bf2f(unsigned short u) {
  union { unsigned int u; float f; } v; v.u = ((unsigned int)u) << 16;
  return v.f;
}

// ---- fused prologue: q/p cast (blocks 0..4095) + 4 weight transposes (4096..8191) ----
__global__ __launch_bounds__(256) void prologue(const float* __restrict__ q,
                                                const float* __restrict__ p,
                                                const float* __restrict__ W0,
                                                const float* __restrict__ W1,
                                                const float* __restrict__ W2,
                                                const float* __restrict__ W3,
                                                unsigned short* __restrict__ qb,
                                                unsigned short* __restrict__ pb,
                                                unsigned short* __restrict__ Wall,
                                                unsigned short* __restrict__ Wot) {
  __shared__ float tile[32][33];
  const int bid = blockIdx.x;
  if (bid < 4096) {
    const int which = bid >> 11;
    const int i = (bid & 2047) * 256 + threadIdx.x;
    const float* x = which ? p : q;
    unsigned short* y = which ? pb : qb;
    const float4* x4 = (const float4*)x;
    float4 a = x4[i * 2], b = x4[i * 2 + 1];
    union { unsigned short u[8]; uint4 v; } o;
    o.u[0] = f2bf(a.x); o.u[1] = f2bf(a.y); o.u[2] = f2bf(a.z); o.u[3] = f2bf(a.w);
    o.u[4] = f2bf(b.x); o.u[5] = f2bf(b.y); o.u[6] = f2bf(b.z); o.u[7] = f2bf(b.w);
    ((uint4*)y)[i] = o.v;
  } else {
    const int r = bid - 4096;
    const int z = r >> 10;
    const int xy = r & 1023;
    const int bx = xy & 31, by = xy >> 5;
    const float* W = (z == 0) ? W0 : (z == 1) ? W1 : (z == 2) ? W2 : W3;
    unsigned short* Wt = (z < 3) ? (Wall + (size_t)z * 1024 * 1024) : Wot;
    const int tx = threadIdx.x & 31, ty = threadIdx.x >> 5;
    const int n0 = bx * 32, k0 = by * 32;
#pragma unroll
    for (int i = 0; i < 4; ++i) {
      int rr = ty + i * 8;
      tile[rr][tx] = W[(size_t)(k0 + rr) * CDIM + n0 + tx];
    }
    __syncthreads();
#pragma unroll
    for (int i = 0; i < 4; ++i) {
      int rr = ty + i * 8;
      Wt[(size_t)(n0 + rr) * CDIM + k0 + tx] = f2bf(tile[tx][rr]);
    }
  }
}

// ---- Fused QKV GEMM (R11-proven optimum): 128x64 tiles, true 2-phase dbuf ----
__global__ __launch_bounds__(256) void gemm_qkv(const unsigned short* __restrict__ qbm,
                                                const unsigned short* __restrict__ pbm,
                                                const unsigned short* __restrict__ Wall,
                                                unsigned short* __restrict__ Qh,
                                                unsigned short* __restrict__ Kh,
                                                unsigned short* __restrict__ Vt) {
  __shared__ unsigned short ldsA[2][128 * 64];
  __shared__ unsigned short ldsB[2][64 * 64];
  const int tid = threadIdx.x, lane = tid & 63, w = tid >> 6;
  const int bid = blockIdx.x;
  const int xcd = bid & 7, local = bid >> 3;
  const int pm = xcd & 3, pn = xcd >> 2;
  const int lm = local & 7, ln = local >> 3;
  const int mblk = pm * 8 + lm;
  const int nblk = pn * 24 + ln;
  const int m0 = mblk * 128;
  const int n0 = nblk * 64;
  const char* Ab = (const char*)((nblk < 16) ? qbm : pbm);
  const char* Bb = (const char*)Wall;
  f32x4_t acc[2][4] = {};

  auto stage = [&](int buf, int kt) {
#pragma unroll
    for (int it = 0; it < 4; ++it) {
      int ob = it * 4096 + w * 1024;
      int o = ob + lane * 16;
      int row = o >> 7, cin = o & 127;
      int cs = cin ^ ((row & 7) << 4);
      gload_lds16(Ab + (size_t)(m0 + row) * 2048 + kt * 128 + cs, (char*)ldsA[buf] + ob);
    }
#pragma unroll
    for (int it = 0; it < 2; ++it) {
      int ob = it * 4096 + w * 1024;
      int o = ob + lane * 16;
      int row = o >> 7, cin = o & 127;
      int cs = cin ^ ((row & 7) << 4);
      gload_lds16(Bb + (size_t)(n0 + row) * 2048 + kt * 128 + cs, (char*)ldsB[buf] + ob);
    }
  };

  stage(0, 0);
  wait_vm0_barrier();
  stage(1, 1);
  for (int kt = 0; kt < 16; ++kt) {
    const char* lA = (const char*)ldsA[kt & 1];
    const char* lB = (const char*)ldsB[kt & 1];
#pragma unroll
    for (int kf = 0; kf < 2; ++kf) {
      int c = kf * 64 + ((lane >> 4) << 4);
      bf16x8_t af[2], bfr[4];
#pragma unroll
      for (int mf = 0; mf < 2; ++mf) {
        int row = w * 32 + mf * 16 + (lane & 15);
        af[mf] = *(const bf16x8_t*)(lA + row * 128 + (c ^ ((row & 7) << 4)));
      }
#pragma unroll
      for (int nf = 0; nf < 4; ++nf) {
        int row = nf * 16 + (lane & 15);
        bfr[nf] = *(const bf16x8_t*)(lB + row * 128 + (c ^ ((row & 7) << 4)));
      }
#pragma unroll
      for (int mf = 0; mf < 2; ++mf)
#pragma unroll
        for (int nf = 0; nf < 4; ++nf)
          acc[mf][nf] = __builtin_amdgcn_mfma_f32_16x16x32_bf16(af[mf], bfr[nf], acc[mf][nf], 0, 0, 0);
    }
    if (kt < 15) {
      wait_vm0_barrier();
      if (kt + 2 < 16) stage(kt & 1, kt + 2);
    }
  }

  const float oscale = (nblk < 16) ? 0.18033688011112042f : 1.0f;  // 0.125*log2(e) for Q
#pragma unroll
  for (int mf = 0; mf < 2; ++mf)
#pragma unroll
    for (int nf = 0; nf < 4; ++nf)
#pragma unroll
      for (int j = 0; j < 4; ++j) {
        int row = m0 + w * 32 + mf * 16 + ((lane >> 4) << 2) + j;
        int col = n0 + nf * 16 + (lane & 15);
        float v = acc[mf][nf][j] * oscale;
        int b = row >> 11, ts = row & 2047;
        if (col < 1024) {
          int h = col >> 6, d = col & 63;
          Qh[(((size_t)(b * 16 + h)) * 2048 + ts) * 64 + d] = bf1(v);
        } else if (col < 2048) {
          int cc = col - 1024, h = cc >> 6, d = cc & 63;
          Kh[(((size_t)(b * 16 + h)) * 2048 + ts) * 64 + d] = bf1(v);
        } else {
          int cc = col - 2048, h = cc >> 6, d = cc & 63;
          Vt[(((size_t)(b * 16 + h)) * 64 + d) * 2048 + ts] = bf1(v);
        }
      }
}

// ---- final GEMM (R11-proven): 128x64 tile, true 2-phase dbuf, reads Ao ----
__global__ __launch_bounds__(256) void gemm_out(const unsigned short* __restrict__ A,
                                                const unsigned short* __restrict__ Bt,
                                                float* __restrict__ Out) {
  __shared__ unsigned short ldsA[2][128 * 64];
  __shared__ unsigned short ldsB[2][64 * 64];
  const int tid = threadIdx.x, lane = tid & 63, w = tid >> 6;
  const int bid = blockIdx.x;
  const int xcd = bid & 7, local = bid >> 3;
  const int pm = xcd & 3, pn = xcd >> 2;
  const int lm = local & 7, ln = local >> 3;
  const int m0 = (pm * 8 + lm) * 128;
  const int n0 = (pn * 8 + ln) * 64;
  const char* Ab = (const char*)A;
  const char* Bb = (const char*)Bt;
  f32x4_t acc[2][4] = {};

  auto stage = [&](int buf, int kt) {
#pragma unroll
    for (int it = 0; it < 4; ++it) {
      int ob = it * 4096 + w * 1024;
      int o = ob + lane * 16;
      int row = o >> 7, cin = o & 127;
      int cs = cin ^ ((row & 7) << 4);
      gload_lds16(Ab + (size_t)(m0 + row) * 2048 + kt * 128 + cs, (char*)ldsA[buf] + ob);
    }
#pragma unroll
    for (int it = 0; it < 2; ++it) {
      int ob = it * 4096 + w * 1024;
      int o = ob + lane * 16;
      int row = o >> 7, cin = o & 127;
      int cs = cin ^ ((row & 7) << 4);
      gload_lds16(Bb + (size_t)(n0 + row) * 2048 + kt * 128 + cs, (char*)ldsB[buf] + ob);
    }
  };

  stage(0, 0);
  wait_vm0_barrier();
  stage(1, 1);
  for (int kt = 0; kt < 16; ++kt) {
    const char* lA = (const char*)ldsA[kt & 1];
    const char* lB = (const char*)ldsB[kt & 1];
#pragma unroll
    for (int kf = 0; kf < 2; ++kf) {
      int c = kf * 64 + ((lane >> 4) << 4);
      bf16x8_t af[2], bfr[4];
#pragma unroll
      for (int mf = 0; mf < 2; ++mf) {
        int row = w * 32 + mf * 16 + (lane & 15);
        af[mf] = *(const bf16x8_t*)(lA + row * 128 + (c ^ ((row & 7) << 4)));
      }
#pragma unroll
      for (int nf = 0; nf < 4; ++nf) {
        int row = nf * 16 + (lane & 15);
        bfr[nf] = *(const bf16x8_t*)(lB + row * 128 + (c ^ ((row & 7) << 4)));
      }
#pragma unroll
      for (int mf = 0; mf < 2; ++mf)
#pragma unroll
        for (int nf = 0; nf < 4; ++nf)
          acc[mf][nf] = __builtin_amdgcn_mfma_f32_16x16x32_bf16(af[mf], bfr[nf], acc[mf][nf], 0, 0, 0);
    }
    if (kt < 15) {
      wait_vm0_barrier();
      if (kt + 2 < 16) stage(kt & 1, kt + 2);
    }
  }

#pragma unroll
  for (int mf = 0; mf < 2; ++mf)
#pragma unroll
    for (int nf = 0; nf < 4; ++nf)
#pragma unroll
      for (int j = 0; j < 4; ++j) {
        int row = m0 + w * 32 + mf * 16 + ((lane >> 4) << 2) + j;
        int col = n0 + nf * 16 + (lane & 15);
        Out[(size_t)row * 1024 + col] = acc[mf][nf][j];
      }
}

// ---- flash attention (R11-proven attn32): swapped-QK^T 32x32, max-free softmax,
// depth-2 pipeline; XCD-locality grid; bf16 O-partials for SPLIT2.
template <int SPLIT>
__global__ __launch_bounds__(256, 3) void attn32(const unsigned short* __restrict__ Qg,
                                                 const unsigned short* __restrict__ Kg,
                                                 const unsigned short* __restrict__ Vtg,
                                                 unsigned short* __restrict__ Ag,
                                                 unsigned short* __restrict__ OpA,
                                                 unsigned short* __restrict__ OpB,
                                                 float* __restrict__ Lp) {
  __shared__ unsigned short ldsK[3][64 * 64];  // 3 x 8 KB
  __shared__ unsigned short ldsV[2][64 * 64];  // 2 x 8 KB
  const int tid = threadIdx.x, lane = tid & 63, w = tid >> 6;
  const int hi = lane >> 5, ql = lane & 31;
  const int bid = blockIdx.x;
  int bh, z, qtile;
  if (SPLIT == 2) {
    int comb = bid & 63;
    qtile = bid >> 6;
    bh = comb >> 1;
    z = comb & 1;
  } else {
    bh = bid & 31;
    qtile = bid >> 5;
    z = 0;
  }
  const int q0 = qtile * 128 + w * 32;
  constexpr int NT = 2048 / SPLIT / 64;
  const int sBeg = z * (2048 / SPLIT);

  bf16x8_t qf[4];
#pragma unroll
  for (int kd = 0; kd < 4; ++kd)
    qf[kd] = *(const bf16x8_t*)(Qg + ((size_t)bh * T_LEN + q0 + ql) * 64 + kd * 16 + hi * 8);

  bf16x8_t ones;
#pragma unroll
  for (int i = 0; i < 8; ++i) ones[i] = (short)0x3F80;  // bf16 1.0

  f32x16_t oacc[2] = {};
  f32x16_t lacc = {};
  const f32x16_t vzero = {};

  const char* Kb = (const char*)(Kg + (size_t)bh * 2048 * 64);
  const char* Vb = (const char*)(Vtg + (size_t)bh * 64 * 2048);

  auto stageK = [&](int slot, int t) {
    int s0 = sBeg + t * 64;
#pragma unroll
    for (int it = 0; it < 2; ++it) {
      int ob = it * 4096 + w * 1024;
      int o = ob + lane * 16;
      int row = o >> 7, cin = o & 127;
      int cs = cin ^ ((row & 7) << 4);
      gload_lds16(Kb + (size_t)s0 * 128 + row * 128 + cs, (char*)ldsK[slot] + ob);
    }
  };
  auto stageV = [&](int slot, int t) {
    int s0 = sBeg + t * 64;
#pragma unroll
    for (int it = 0; it < 2; ++it) {
      int ob = it * 4096 + w * 1024;
      int o = ob + lane * 16;
      int row = o >> 7, cin = o & 127;
      int cs = cin ^ ((row & 7) << 4);
      gload_lds16(Vb + (size_t)s0 * 2 + (size_t)row * 4096 + cs, (char*)ldsV[slot] + ob);
    }
  };

  auto qk = [&](f32x16_t (&s)[2], int slot) {
    const char* lK = (const char*)ldsK[slot];
#pragma unroll
    for (int sub = 0; sub < 2; ++sub) {
      int row = sub * 32 + ql;
      int swz = (row & 7) << 4;
#pragma unroll
      for (int kd = 0; kd < 4; ++kd) {
        bf16x8_t kfrag = *(const bf16x8_t*)(lK + row * 128 + ((kd * 32 + hi * 16) ^ swz));
        s[sub] = __builtin_amdgcn_mfma_f32_32x32x16_bf16(kfrag, qf[kd], s[sub], 0, 0, 0);
      }
    }
  };

  auto consume = [&](f32x16_t (&s)[2], int vslot) {
    const char* lV = (const char*)ldsV[vslot];
#pragma unroll
    for (int ks = 0; ks < 4; ++ks) {
      const int sub = ks >> 1, mA = (ks & 1) * 2, mB = mA + 1;
      float e0 = fexp2(s[sub][4 * mA + 0]), e1 = fexp2(s[sub][4 * mA + 1]);
      float e2 = fexp2(s[sub][4 * mA + 2]), e3 = fexp2(s[sub][4 * mA + 3]);
      float e4 = fexp2(s[sub][4 * mB + 0]), e5 = fexp2(s[sub][4 * mB + 1]);
      float e6 = fexp2(s[sub][4 * mB + 2]), e7 = fexp2(s[sub][4 * mB + 3]);
      unsigned int a0 = pk_bf16(e0, e1), a1 = pk_bf16(e2, e3);
      unsigned int b0 = pk_bf16(e4, e5), b1 = pk_bf16(e6, e7);
      asm("v_permlane32_swap_b32 %0, %1" : "+v"(a0), "+v"(b0));
      asm("v_permlane32_swap_b32 %0, %1" : "+v"(a1), "+v"(b1));
      union { unsigned int u[4]; bf16x8_t v; } P;
      P.u[0] = a0; P.u[1] = a1; P.u[2] = b0; P.u[3] = b1;
      lacc = __builtin_amdgcn_mfma_f32_32x32x16_bf16(P.v, ones, lacc, 0, 0, 0);
#pragma unroll
      for (int dt = 0; dt < 2; ++dt) {
        int row = dt * 32 + ql;
        bf16x8_t vfrag = *(const bf16x8_t*)(lV + row * 128 + ((ks * 32 + hi * 16) ^ ((row & 7) << 4)));
        oacc[dt] = __builtin_amdgcn_mfma_f32_32x32x16_bf16(P.v, vfrag, oacc[dt], 0, 0, 0);
      }
    }
  };

  f32x16_t sA[2] = {}, sB[2] = {};
  stageK(0, 0);
  stageV(0, 0);
  stageK(1, 1);
  __syncthreads();
  qk(sA, 0);

  for (int i = 0; i < NT; i += 2) {
    if (i + 2 < NT) stageK((i + 2) % 3, i + 2);
    if (i + 1 < NT) stageV((i + 1) & 1, i + 1);
    if (i + 1 < NT) { sB[0] = vzero; sB[1] = vzero; qk(sB, (i + 1) % 3); }
    consume(sA, i & 1);
    __syncthreads();
    if (i + 1 < NT) {
      if (i + 3 < NT) stageK((i + 3) % 3, i + 3);
      if (i + 2 < NT) stageV((i + 2) & 1, i + 2);
      if (i + 2 < NT) { sA[0] = vzero; sA[1] = vzero; qk(sA, (i + 2) % 3); }
      consume(sB, (i + 1) & 1);
      __syncthreads();
    }
  }

  const int b = bh >> 4, h = bh & 15;
  if (SPLIT == 1) {
#pragma unroll
    for (int grp = 0; grp < 4; ++grp)
#pragma unroll
      for (int r2 = 0; r2 < 4; ++r2) {
        int reg = grp * 4 + r2;
        float linv = 1.0f / lacc[reg];
        int t = q0 + 4 * hi + 8 * grp + r2;
#pragma unroll
        for (int dt = 0; dt < 2; ++dt) {
          int col = h * 64 + dt * 32 + ql;
          float v = oacc[dt][reg] * linv;
          Ag[((size_t)b * T_LEN + t) * CDIM + col] = bf1(v);
        }
      }
  } else {
    unsigned short* Op = z ? OpB : OpA;
#pragma unroll
    for (int grp = 0; grp < 4; ++grp)
#pragma unroll
      for (int r2 = 0; r2 < 4; ++r2) {
        int reg = grp * 4 + r2;
        int t = q0 + 4 * hi + 8 * grp + r2;
#pragma unroll
        for (int dt = 0; dt < 2; ++dt)
          Op[((size_t)b * T_LEN + t) * CDIM + h * 64 + dt * 32 + ql] = bf1(oacc[dt][reg]);
        if (ql == 0)
          Lp[(((size_t)z * 2 + b) * 16 + h) * T_LEN + t] = lacc[reg];
      }
  }
}

// ---- combine 2-way KV-split bf16 partials (R11-proven) ----
__global__ __launch_bounds__(256) void attn_combine(const unsigned short* __restrict__ O0,
                                                    const unsigned short* __restrict__ O1,
                                                    const float* __restrict__ Lp,
                                                    unsigned short* __restrict__ Ag) {
  int i = blockIdx.x * 256 + threadIdx.x;
  int c8 = i & 127, bt = i >> 7;
  int b = bt >> 11, t = bt & 2047;
  int c = c8 * 8, h = c >> 6;
  float l0 = Lp[(((size_t)0 * 2 + b) * 16 + h) * T_LEN + t];
  float l1 = Lp[(((size_t)1 * 2 + b) * 16 + h) * T_LEN + t];
  float inv = 1.0f / (l0 + l1);
  size_t off = (size_t)bt * CDIM + c;
  union { unsigned short u[8]; uint4 v; } a, bb, o;
  a.v  = *(const uint4*)(O0 + off);
  bb.v = *(const uint4*)(O1 + off);
  float s[8];
#pragma unroll
  for (int k = 0; k < 8; ++k) s[k] = (bf2f(a.u[k]) + bf2f(bb.u[k])) * inv;
  unsigned int p0 = pk_bf16(s[0], s[1]), p1 = pk_bf16(s[2], s[3]);
  unsigned int p2 = pk_bf16(s[4], s[5]), p3 = pk_bf16(s[6], s[7]);
  o.v = make_uint4(p0, p1, p2, p3);
  *(uint4*)(Ag + off) = o.v;
}

extern "C" void kernel_launch(void* const* d_in, const int* in_sizes, int n_in,
                              void* d_out, int out_size, void* d_ws, size_t ws_size,
                              hipStream_t stream) {
  const float* q  = (const float*)d_in[0];
  const float* p  = (const float*)d_in[1];
  const float* Wq = (const float*)d_in[2];
  const float* Wk = (const float*)d_in[3];
  const float* Wv = (const float*)d_in[4];
  const float* Wo = (const float*)d_in[5];

  char* ws = (char*)d_ws;
  const size_t MB = (size_t)1 << 20;
  unsigned short* qb   = (unsigned short*)(ws);            // 8 MB (dead after gemm_qkv)
  unsigned short* pb   = (unsigned short*)(ws + 8 * MB);   // 8 MB (dead after gemm_qkv)
  unsigned short* Wall = (unsigned short*)(ws + 16 * MB);  // 6 MB (dead after gemm_qkv)
  unsigned short* Wot  = (unsigned short*)(ws + 22 * MB);  // 2 MB
  unsigned short* Qh   = (unsigned short*)(ws + 24 * MB);  // 8 MB [B,H,T,D]
  unsigned short* Kh   = (unsigned short*)(ws + 32 * MB);  // 8 MB [B,H,S,D]
  unsigned short* Vt   = (unsigned short*)(ws + 40 * MB);  // 8 MB [B,H,D,S]
  unsigned short* Ao   = (unsigned short*)(ws + 48 * MB);  // 8 MB [B,T,C]

  prologue<<<8192, 256, 0, stream>>>(q, p, Wq, Wk, Wv, Wo, qb, pb, Wall, Wot);

  gemm_qkv<<<1536, 256, 0, stream>>>(qb, pb, Wall, Qh, Kh, Vt);

  if (ws_size >= 73 * MB) {
    unsigned short* O0 = (unsigned short*)(ws);            // overlays qb (dead)
    unsigned short* O1 = (unsigned short*)(ws + 56 * MB);
    float* Lp = (float*)(ws + 72 * MB);
    attn32<2><<<1024, 256, 0, stream>>>(Qh, Kh, Vt, nullptr, O0, O1, Lp);
    attn_combine<<<2048, 256, 0, stream>>>(O0, O1, Lp, Ao);
  } else {
    attn32<1><<<512, 256, 0, stream>>>(Qh, Kh, Vt, Ao, nullptr, nullptr, nullptr);
  }

  gemm_out<<<512, 256, 0, stream>>>(Ao, Wot, (float*)d_out);
}